// Round 1
// 377.740 us; speedup vs baseline: 1.0344x; 1.0344x over previous
//
#include <hip/hip_runtime.h>
#include <hip/hip_bf16.h>
#include <cstdint>

// Problem constants
#define BB 2
#define SS 2048
#define DD 1024
#define HH 16
#define HDIM 64
#define MROWS (BB*SS)   // 4096

typedef __bf16 bf16;
using bf16x8 = __bf16 __attribute__((ext_vector_type(8)));
using bf16x4 = __bf16 __attribute__((ext_vector_type(4)));
using bf16x2 = __bf16 __attribute__((ext_vector_type(2)));
using f32x4  = float __attribute__((ext_vector_type(4)));

__device__ __forceinline__ float gelu_exact(float x) {
    return 0.5f * x * (1.f + erff(x * 0.70710678118654752f));
}

// global->LDS direct DMA, 16B per lane (lane i deposits at base + i*16).
__device__ __forceinline__ void stage16(const bf16* g, bf16* lds_chunk_base, int lane) {
#if __has_builtin(__builtin_amdgcn_global_load_lds)
    __builtin_amdgcn_global_load_lds((const __attribute__((address_space(1))) void*)g,
                                     (__attribute__((address_space(3))) void*)lds_chunk_base,
                                     16, 0, 0);
#else
    *(bf16x8*)(lds_chunk_base + lane * 8) = *(const bf16x8*)g;
#endif
}

// ---------------- fused prep: cast x, pack mask, transpose all weights ----------------
// block ranges: [0,4096) cast x | [4096,20480) pack mask | [20480,32768) transposes
__global__ __launch_bounds__(256) void prep_kernel(
    const float* __restrict__ x, bf16* __restrict__ x_b,
    const int* __restrict__ mask, unsigned long long* __restrict__ maskb,
    const float* __restrict__ Wq, const float* __restrict__ Wk,
    const float* __restrict__ Wv, const float* __restrict__ Wo,
    const float* __restrict__ W1, const float* __restrict__ W2,
    bf16* __restrict__ Wqkv_t, bf16* __restrict__ Wo_t,
    bf16* __restrict__ W1_t, bf16* __restrict__ W2_t) {
    const int bid = blockIdx.x;
    if (bid < 4096) {
        int i = bid * 256 + threadIdx.x;
        float4 v = ((const float4*)x)[i];
        bf16x4 o;
        o[0] = (bf16)v.x; o[1] = (bf16)v.y; o[2] = (bf16)v.z; o[3] = (bf16)v.w;
        *(bf16x4*)(x_b + (size_t)i * 4) = o;
        return;
    }
    if (bid < 20480) {
        int gid = (bid - 4096) * 256 + threadIdx.x;
        int mv = mask[gid];
        unsigned long long bal = __ballot(mv == 1);
        if ((threadIdx.x & 63) == 0) maskb[gid >> 6] = bal;
        return;
    }
    int t = bid - 20480;
    const float* W; bf16* Wt; int K, N, bx, by;
    if (t < 4096) {
        int wsel = t >> 10;
        int tt = t & 1023;
        W  = (wsel == 0) ? Wq : (wsel == 1) ? Wk : (wsel == 2) ? Wv : Wo;
        Wt = (wsel == 3) ? Wo_t : (Wqkv_t + (size_t)wsel * 1024 * 1024);
        K = 1024; N = 1024; bx = (tt & 31) * 32; by = (tt >> 5) * 32;
    } else if (t < 8192) {
        int tt = t - 4096;
        W = W1; Wt = W1_t; K = 1024; N = 4096;
        bx = (tt & 127) * 32; by = (tt >> 7) * 32;
    } else {
        int tt = t - 8192;
        W = W2; Wt = W2_t; K = 4096; N = 1024;
        bx = (tt & 31) * 32; by = (tt >> 5) * 32;
    }
    __shared__ float tile[32][33];
    int tx = threadIdx.x & 31;
    int ty = threadIdx.x >> 5;
#pragma unroll
    for (int j = 0; j < 4; ++j)
        tile[ty + j * 8][tx] = W[(size_t)(by + ty + j * 8) * N + bx + tx];
    __syncthreads();
#pragma unroll
    for (int j = 0; j < 4; ++j)
        Wt[(size_t)(bx + ty + j * 8) * K + by + tx] = (bf16)tile[tx][ty + j * 8];
}

// ---------------- bf16 MFMA GEMM: C = A(M x ldk) * Bt(N x ldk)^T, 128x128 tile ----------------
// K = slice length along k (blockIdx.z selects slice); ldk = full row stride.
// EPI: 0 = store bf16 raw; 2 = +bias,gelu store bf16; 4 = raw fp32 partial to (z ? C2 : C).
template <int EPI>
__global__ __launch_bounds__(256, 3) void gemm_bt(const bf16* __restrict__ A,
                                                  const bf16* __restrict__ Bt,
                                                  void* __restrict__ C,
                                                  void* __restrict__ C2,
                                                  const float* __restrict__ bias,
                                                  int M, int N, int K, int ldk) {
    __shared__ __align__(16) bf16 As[128 * 64];
    __shared__ __align__(16) bf16 Bs[128 * 64];
    const int tid  = threadIdx.x;
    const int lane = tid & 63;
    const int wave = tid >> 6;
    const int l16  = lane & 15;
    const int quad = lane >> 4;
    const int wm = wave >> 1, wn = wave & 1;
    const int m0 = blockIdx.y * 128, n0 = blockIdx.x * 128;
    const int z  = blockIdx.z;
    A  += (size_t)z * K;
    Bt += (size_t)z * K;

    f32x4 acc[4][4];
#pragma unroll
    for (int i = 0; i < 4; ++i)
#pragma unroll
        for (int j = 0; j < 4; ++j) acc[i][j] = (f32x4){0.f, 0.f, 0.f, 0.f};

    const int nsteps = K >> 6;
    for (int kt = 0; kt < nsteps; ++kt) {
        const int kbase = kt << 6;
#pragma unroll
        for (int c = 0; c < 4; ++c) {
            int chunk = wave * 4 + c;
            int gi = chunk * 64 + lane;
            int m  = gi >> 3;
            int cp = gi & 7;
            int g  = cp ^ (m & 7);
            stage16(A  + (size_t)(m0 + m) * ldk + kbase + g * 8, As + chunk * 512, lane);
            stage16(Bt + (size_t)(n0 + m) * ldk + kbase + g * 8, Bs + chunk * 512, lane);
        }
        __syncthreads();
#pragma unroll
        for (int ks = 0; ks < 2; ++ks) {
            bf16x8 af[4], bfr[4];
#pragma unroll
            for (int i = 0; i < 4; ++i) {
                int m = wm * 64 + i * 16 + l16;
                int g = ks * 4 + quad;
                af[i]  = *(const bf16x8*)(As + m * 64 + ((g ^ (m & 7)) * 8));
                int n = wn * 64 + i * 16 + l16;
                bfr[i] = *(const bf16x8*)(Bs + n * 64 + ((g ^ (n & 7)) * 8));
            }
#pragma unroll
            for (int i = 0; i < 4; ++i)
#pragma unroll
                for (int j = 0; j < 4; ++j)
                    acc[i][j] = __builtin_amdgcn_mfma_f32_16x16x32_bf16(af[i], bfr[j], acc[i][j], 0, 0, 0);
        }
        __syncthreads();
    }

    float* Cz = (EPI == 4) ? (z ? (float*)C2 : (float*)C) : nullptr;
#pragma unroll
    for (int i = 0; i < 4; ++i) {
        int row = m0 + wm * 64 + i * 16 + quad * 4;
#pragma unroll
        for (int j = 0; j < 4; ++j) {
            int col = n0 + wn * 64 + j * 16 + l16;
            float bv = (EPI == 2) ? bias[col] : 0.f;
#pragma unroll
            for (int r = 0; r < 4; ++r) {
                float v = acc[i][j][r];
                if (EPI == 2) v = gelu_exact(v + bv);
                size_t idx = (size_t)(row + r) * N + col;
                if (EPI == 4) Cz[idx] = v;
                else          ((bf16*)C)[idx] = (bf16)v;
            }
        }
    }
}

// ---------------- flash attention (r9: reg-staged K/V prefetch pipeline) ----------------
// grid: (S/64, B*H), block 256 (4 waves; wave owns 16 query rows). BK=128.
// Changes vs r7/r8:
//   * K staged via registers (not global_load_lds); K(kt+1)/V(kt+1)/mask(kt+1)
//     prefetched into regs at start of compute phase -> HBM latency hidden under
//     compute instead of exposed between the two barriers (T14, +17% in m214).
//   * SCL folded into Q at load (kills 32 v_mul per wave-kt).
//   * lsum computed by extra MFMA against constant ones-fragment (kills 32 v_add
//     per wave-kt + epilogue shuffle tree; lands in C/D layout row=quad*4+r).
//   * s_setprio(1) around MFMA clusters (T5, +4-7% attn per m191).
__global__ __launch_bounds__(256, 4) void flash_attn(const bf16* __restrict__ qkv,
                                                     const unsigned long long* __restrict__ maskb,
                                                     bf16* __restrict__ o) {
    __shared__ __align__(16) bf16 Ks[128 * 64];    // swizzled packed [t][g^(t&7)]
    __shared__ __align__(16) bf16 Vts[64 * 136];   // [d][tc], tc = t-permuted, pad 8
    const int tid  = threadIdx.x;
    const int lane = tid & 63;
    const int wave = tid >> 6;
    const int l16  = lane & 15;
    const int quad = lane >> 4;
    const int bh = blockIdx.y;
    const int b = bh >> 4, h = bh & 15;
    const int q0 = blockIdx.x * 64;
    const size_t rowb = (size_t)b * SS;
    const float SCL = 0.18033688011112042f;  // 0.125 * log2(e)

    // Q fragments, pre-scaled by SCL (so softmax is exp2(st) directly)
    const size_t qrow = (rowb + q0 + wave * 16 + l16) * 3072 + h * 64;
    bf16x8 qf[2];
    {
        bf16x8 q0r = *(const bf16x8*)(qkv + qrow + quad * 8);
        bf16x8 q1r = *(const bf16x8*)(qkv + qrow + 32 + quad * 8);
#pragma unroll
        for (int j = 0; j < 8; ++j) {
            qf[0][j] = (bf16)((float)q0r[j] * SCL);
            qf[1][j] = (bf16)((float)q1r[j] * SCL);
        }
    }

    f32x4 oacc[4];
#pragma unroll
    for (int d = 0; d < 4; ++d) oacc[d] = (f32x4){0.f, 0.f, 0.f, 0.f};
    f32x4 lacc = (f32x4){0.f, 0.f, 0.f, 0.f};
    const int mrow32 = (q0 + wave * 16 + l16) * 32;

    bf16x8 ones;
#pragma unroll
    for (int j = 0; j < 8; ++j) ones[j] = (bf16)1.0f;

    // V staging geometry: t-pair = 2*lane, granule = wave + 4c; permuted col tc
    // groups the 8 k-slots of each (kc,quad) contiguously.
    const int vt_tc = (lane >> 4) * 32 + ((lane >> 1) & 3) * 8 + ((lane >> 3) & 1) * 4 + 2 * (lane & 1);

    // K staging geometry (constant across kt): 4 chunks per wave
    int kst[4], ksg[4];
#pragma unroll
    for (int c = 0; c < 4; ++c) {
        int gi = (wave * 4 + c) * 64 + lane;
        kst[c] = gi >> 3;
        ksg[c] = (gi & 7) ^ (kst[c] & 7);
    }

    // -------- prologue: prefetch tile 0 into registers --------
    bf16x8 kreg[4], vreg[4];
    ulonglong2 mwreg;
#pragma unroll
    for (int c = 0; c < 4; ++c)
        kreg[c] = *(const bf16x8*)(qkv + (rowb + kst[c]) * 3072 + 1024 + h * 64 + ksg[c] * 8);
#pragma unroll
    for (int c = 0; c < 2; ++c) {
        const bf16* vg = qkv + (rowb + 2 * lane) * 3072 + 2048 + h * 64 + (wave + 4 * c) * 8;
        vreg[2 * c]     = *(const bf16x8*)(vg);
        vreg[2 * c + 1] = *(const bf16x8*)(vg + 3072);
    }
    mwreg = *(const ulonglong2*)(maskb + mrow32);

    for (int kt = 0; kt < SS / 128; ++kt) {
        __syncthreads();  // previous tile's compute done before overwrite
        // commit staged K (swizzled layout identical to old DMA deposit)
#pragma unroll
        for (int c = 0; c < 4; ++c)
            *(bf16x8*)(Ks + (wave * 4 + c) * 512 + lane * 8) = kreg[c];
        // commit staged V, transposed+permuted
#pragma unroll
        for (int c = 0; c < 2; ++c) {
            int d8 = (wave + 4 * c) * 8;
#pragma unroll
            for (int j = 0; j < 8; ++j) {
                bf16x2 pr; pr[0] = vreg[2 * c][j]; pr[1] = vreg[2 * c + 1][j];
                *(bf16x2*)(Vts + (d8 + j) * 136 + vt_tc) = pr;
            }
        }
        ulonglong2 mw = mwreg;
        __syncthreads();

        // prefetch next tile into regs: latency hides under this tile's compute.
        // (must be AFTER the barrier: __syncthreads drains vmcnt(0).)
        if (kt + 1 < SS / 128) {
            const int t0n = (kt + 1) * 128;
#pragma unroll
            for (int c = 0; c < 4; ++c)
                kreg[c] = *(const bf16x8*)(qkv + (rowb + t0n + kst[c]) * 3072 + 1024 + h * 64 + ksg[c] * 8);
#pragma unroll
            for (int c = 0; c < 2; ++c) {
                const bf16* vg = qkv + (rowb + t0n + 2 * lane) * 3072 + 2048 + h * 64 + (wave + 4 * c) * 8;
                vreg[2 * c]     = *(const bf16x8*)(vg);
                vreg[2 * c + 1] = *(const bf16x8*)(vg + 3072);
            }
            mwreg = *(const ulonglong2*)(maskb + mrow32 + (kt + 1) * 2);
        }

        // S^T tiles: D[t][s], t = tg*16 + quad*4 + reg, s = l16
        f32x4 st[8];
        __builtin_amdgcn_s_setprio(1);
#pragma unroll
        for (int tg = 0; tg < 8; ++tg) {
            int tl = tg * 16 + l16;
            bf16x8 a0 = *(const bf16x8*)(Ks + tl * 64 + ((quad       ^ (tl & 7)) * 8));
            bf16x8 a1 = *(const bf16x8*)(Ks + tl * 64 + (((4 + quad) ^ (tl & 7)) * 8));
            f32x4 s = (f32x4){0.f, 0.f, 0.f, 0.f};
            s = __builtin_amdgcn_mfma_f32_16x16x32_bf16(a0, qf[0], s, 0, 0, 0);
            s = __builtin_amdgcn_mfma_f32_16x16x32_bf16(a1, qf[1], s, 0, 0, 0);
            st[tg] = s;
        }
        __builtin_amdgcn_s_setprio(0);

        // exp2 + mask-zero + pack P fragments (Q pre-scaled: no mul here)
        unsigned long long s0 = mw.x >> (quad * 4);
        unsigned long long s1 = mw.y >> (quad * 4);
        bf16x8 pva[4];
#pragma unroll
        for (int tg = 0; tg < 8; ++tg) {
            unsigned int bits = (unsigned int)(((tg < 4) ? s0 : s1) >> ((tg & 3) * 16));
#pragma unroll
            for (int r = 0; r < 4; ++r) {
                float p = __builtin_amdgcn_exp2f(st[tg][r]);
                p = ((bits >> r) & 1u) ? 0.f : p;
                pva[tg >> 1][(tg & 1) * 4 + r] = (bf16)p;
            }
        }

        // O += P*V ; lsum += P*ones (row-sums on the MFMA pipe, layout row=quad*4+r)
        __builtin_amdgcn_s_setprio(1);
#pragma unroll
        for (int kc = 0; kc < 4; ++kc) {
#pragma unroll
            for (int dg = 0; dg < 4; ++dg) {
                bf16x8 bfrag = *(const bf16x8*)(Vts + (dg * 16 + l16) * 136 + kc * 32 + quad * 8);
                oacc[dg] = __builtin_amdgcn_mfma_f32_16x16x32_bf16(pva[kc], bfrag, oacc[dg], 0, 0, 0);
            }
            lacc = __builtin_amdgcn_mfma_f32_16x16x32_bf16(pva[kc], ones, lacc, 0, 0, 0);
        }
        __builtin_amdgcn_s_setprio(0);
    }

    // epilogue: lacc[r] already holds the P row-sum for q-row quad*4+r
#pragma unroll
    for (int r = 0; r < 4; ++r) {
        float inv_l = 1.f / lacc[r];
        bf16* orow = o + (rowb + q0 + wave * 16 + quad * 4 + r) * DD + h * 64;
#pragma unroll
        for (int dg = 0; dg < 4; ++dg)
            orow[dg * 16 + l16] = (bf16)(oacc[dg][r] * inv_l);
    }
}

// ---------------- fused split-K reduce + bias (+gelu) + residual LayerNorm ----------------
// out = resid + LN(act(p0 + p1 + bias)) * g + b ;  act = gelu if GELU else identity
template <bool GELU, bool WB16>
__global__ __launch_bounds__(256) void ln_fused(const float* __restrict__ resid,
                                                const float* __restrict__ p0,
                                                const float* __restrict__ p1,
                                                const float* __restrict__ bias,
                                                const float* __restrict__ g,
                                                const float* __restrict__ bb,
                                                float* __restrict__ outf,
                                                bf16* __restrict__ outb) {
    const int row = blockIdx.x;
    const int tid = threadIdx.x;
    const size_t base = (size_t)row * DD + tid * 4;
    float4 a0 = *(const float4*)(p0 + base);
    float4 a1 = *(const float4*)(p1 + base);
    float4 bz = *(const float4*)(bias + tid * 4);
    float ax = a0.x + a1.x + bz.x;
    float ay = a0.y + a1.y + bz.y;
    float az = a0.z + a1.z + bz.z;
    float aw = a0.w + a1.w + bz.w;
    if (GELU) { ax = gelu_exact(ax); ay = gelu_exact(ay); az = gelu_exact(az); aw = gelu_exact(aw); }
    float s1 = ax + ay + az + aw;
    float s2 = ax * ax + ay * ay + az * az + aw * aw;
#pragma unroll
    for (int off = 32; off; off >>= 1) {
        s1 += __shfl_xor(s1, off, 64);
        s2 += __shfl_xor(s2, off, 64);
    }
    __shared__ float red[8];
    if ((tid & 63) == 0) { red[(tid >> 6) * 2] = s1; red[(tid >> 6) * 2 + 1] = s2; }
    __syncthreads();
    s1 = red[0] + red[2] + red[4] + red[6];
    s2 = red[1] + red[3] + red[5] + red[7];
    float mean = s1 * (1.f / DD);
    float var  = s2 * (1.f / DD) - mean * mean;
    float rs = rsqrtf(var + 1e-5f);
    float4 gv = *(const float4*)(g + tid * 4);
    float4 bv = *(const float4*)(bb + tid * 4);
    float4 rv = *(const float4*)(resid + base);
    float y0 = rv.x + (ax - mean) * rs * gv.x + bv.x;
    float y1 = rv.y + (ay - mean) * rs * gv.y + bv.y;
    float y2 = rv.z + (az - mean) * rs * gv.z + bv.z;
    float y3 = rv.w + (aw - mean) * rs * gv.w + bv.w;
    float4 yo = make_float4(y0, y1, y2, y3);
    *(float4*)(outf + base) = yo;
    if (WB16) {
        bf16x4 ob;
        ob[0] = (bf16)y0; ob[1] = (bf16)y1; ob[2] = (bf16)y2; ob[3] = (bf16)y3;
        *(bf16x4*)(outb + base) = ob;
    }
}

// ---------------- launcher ----------------
extern "C" void kernel_launch(void* const* d_in, const int* in_sizes, int n_in,
                              void* d_out, int out_size, void* d_ws, size_t ws_size,
                              hipStream_t stream) {
    const float* x    = (const float*)d_in[0];
    const int*   mask = (const int*)d_in[1];
    const float* Wq   = (const float*)d_in[2];
    const float* Wk   = (const float*)d_in[3];
    const float* Wv   = (const float*)d_in[4];
    const float* Wo   = (const float*)d_in[5];
    const float* bo   = (const float*)d_in[6];
    const float* ln1g = (const float*)d_in[7];
    const float* ln1b = (const float*)d_in[8];
    const float* W1   = (const float*)d_in[9];
    const float* b1   = (const float*)d_in[10];
    const float* W2   = (const float*)d_in[11];
    const float* b2   = (const float*)d_in[12];
    const float* ln2g = (const float*)d_in[13];
    const float* ln2b = (const float*)d_in[14];

    char* w = (char*)d_ws;
    bf16* Wqkv_t = (bf16*)w; w += (size_t)3072 * 1024 * 2;   // 6 MB
    bf16* Wo_t   = (bf16*)w; w += (size_t)1024 * 1024 * 2;   // 2 MB
    bf16* W1_t   = (bf16*)w; w += (size_t)4096 * 1024 * 2;   // 8 MB
    bf16* W2_t   = (bf16*)w; w += (size_t)1024 * 4096 * 2;   // 8 MB
    bf16* x_b    = (bf16*)w; w += (size_t)MROWS * DD * 2;    // 8 MB (then o_b, x1_b)
    bf16* qkv    = (bf16*)w; w += (size_t)MROWS * 3072 * 2;  // 24 MB (then FFN2 p1)
    float* R     = (float*)w; w += (size_t)MROWS * DD * 8;   // 32 MB (O-proj p0/p1, then h_b)
    float* x1_f  = (float*)w; w += (size_t)MROWS * DD * 4;   // 16 MB
    unsigned long long* maskb = (unsigned long long*)w; w += (size_t)SS * 32 * 8;  // 0.5 MB  (total 104.5)
    bf16* o_b  = x_b;                 // alive: attention -> O-proj
    bf16* x1_b = x_b;                 // alive: LN1 -> FFN1
    float* op0 = R;                   // O-proj partial z=0
    float* op1 = R + (size_t)MROWS * DD;  // O-proj partial z=1
    bf16*  h_b = (bf16*)R;            // FFN1 out (32 MB; partials dead by then)
    float* fp0 = (float*)d_out;       // FFN2 partial z=0 (reduced in-place by LN2)
    float* fp1 = (float*)qkv;         // FFN2 partial z=1 (qkv dead after flash)

    // fused prep (one launch)
    prep_kernel<<<32768, 256, 0, stream>>>(x, x_b, mask, maskb,
                                           Wq, Wk, Wv, Wo, W1, W2,
                                           Wqkv_t, Wo_t, W1_t, W2_t);

    // QKV projection: [4096,1024] x [1024,3072] -> qkv bf16
    gemm_bt<0><<<dim3(24, 32, 1), 256, 0, stream>>>(x_b, Wqkv_t, qkv, nullptr, nullptr, MROWS, 3072, 1024, 1024);
    // attention
    flash_attn<<<dim3(SS / 64, BB * HH), 256, 0, stream>>>(qkv, maskb, o_b);
    // O-proj, split-K=2 -> fp32 partials (bias deferred to LN1)
    gemm_bt<4><<<dim3(8, 32, 2), 256, 0, stream>>>(o_b, Wo_t, op0, op1, nullptr, MROWS, 1024, 512, 1024);
    // x1 = x + LN(op0+op1+bo)
    ln_fused<false, true><<<MROWS, 256, 0, stream>>>(x, op0, op1, bo, ln1g, ln1b, x1_f, x1_b);
    // FFN1: gelu(x1@W1 + b1) -> bf16
    gemm_bt<2><<<dim3(32, 32, 1), 256, 0, stream>>>(x1_b, W1_t, h_b, nullptr, b1, MROWS, 4096, 1024, 1024);
    // FFN2, split-K=2 -> fp32 partials (bias+gelu deferred to LN2)
    gemm_bt<4><<<dim3(8, 32, 2), 256, 0, stream>>>(h_b, W2_t, fp0, fp1, nullptr, MROWS, 1024, 2048, 4096);
    // out = x1 + LN(gelu(fp0+fp1+b2))  (fp32, in-place on d_out)
    ln_fused<true, false><<<MROWS, 256, 0, stream>>>(x1_f, fp0, fp1, b2, ln2g, ln2b, (float*)d_out, nullptr);
}

// Round 2
// 377.237 us; speedup vs baseline: 1.0358x; 1.0013x over previous
//
#include <hip/hip_runtime.h>
#include <hip/hip_bf16.h>
#include <cstdint>

// Problem constants
#define BB 2
#define SS 2048
#define DD 1024
#define HH 16
#define HDIM 64
#define MROWS (BB*SS)   // 4096

typedef __bf16 bf16;
using bf16x8 = __bf16 __attribute__((ext_vector_type(8)));
using bf16x4 = __bf16 __attribute__((ext_vector_type(4)));
using bf16x2 = __bf16 __attribute__((ext_vector_type(2)));
using f32x4  = float __attribute__((ext_vector_type(4)));

__device__ __forceinline__ float gelu_exact(float x) {
    return 0.5f * x * (1.f + erff(x * 0.70710678118654752f));
}

// global->LDS direct DMA, 16B per lane (lane i deposits at base + i*16).
__device__ __forceinline__ void stage16(const bf16* g, bf16* lds_chunk_base, int lane) {
#if __has_builtin(__builtin_amdgcn_global_load_lds)
    __builtin_amdgcn_global_load_lds((const __attribute__((address_space(1))) void*)g,
                                     (__attribute__((address_space(3))) void*)lds_chunk_base,
                                     16, 0, 0);
#else
    *(bf16x8*)(lds_chunk_base + lane * 8) = *(const bf16x8*)g;
#endif
}

// ---------------- fused prep: cast x, pack mask, transpose all weights ----------------
// block ranges: [0,4096) cast x | [4096,20480) pack mask | [20480,32768) transposes
__global__ __launch_bounds__(256) void prep_kernel(
    const float* __restrict__ x, bf16* __restrict__ x_b,
    const int* __restrict__ mask, unsigned long long* __restrict__ maskb,
    const float* __restrict__ Wq, const float* __restrict__ Wk,
    const float* __restrict__ Wv, const float* __restrict__ Wo,
    const float* __restrict__ W1, const float* __restrict__ W2,
    bf16* __restrict__ Wqkv_t, bf16* __restrict__ Wo_t,
    bf16* __restrict__ W1_t, bf16* __restrict__ W2_t) {
    const int bid = blockIdx.x;
    if (bid < 4096) {
        int i = bid * 256 + threadIdx.x;
        float4 v = ((const float4*)x)[i];
        bf16x4 o;
        o[0] = (bf16)v.x; o[1] = (bf16)v.y; o[2] = (bf16)v.z; o[3] = (bf16)v.w;
        *(bf16x4*)(x_b + (size_t)i * 4) = o;
        return;
    }
    if (bid < 20480) {
        int gid = (bid - 4096) * 256 + threadIdx.x;
        int mv = mask[gid];
        unsigned long long bal = __ballot(mv == 1);
        if ((threadIdx.x & 63) == 0) maskb[gid >> 6] = bal;
        return;
    }
    int t = bid - 20480;
    const float* W; bf16* Wt; int K, N, bx, by;
    if (t < 4096) {
        int wsel = t >> 10;
        int tt = t & 1023;
        W  = (wsel == 0) ? Wq : (wsel == 1) ? Wk : (wsel == 2) ? Wv : Wo;
        Wt = (wsel == 3) ? Wo_t : (Wqkv_t + (size_t)wsel * 1024 * 1024);
        K = 1024; N = 1024; bx = (tt & 31) * 32; by = (tt >> 5) * 32;
    } else if (t < 8192) {
        int tt = t - 4096;
        W = W1; Wt = W1_t; K = 1024; N = 4096;
        bx = (tt & 127) * 32; by = (tt >> 7) * 32;
    } else {
        int tt = t - 8192;
        W = W2; Wt = W2_t; K = 4096; N = 1024;
        bx = (tt & 31) * 32; by = (tt >> 5) * 32;
    }
    __shared__ float tile[32][33];
    int tx = threadIdx.x & 31;
    int ty = threadIdx.x >> 5;
#pragma unroll
    for (int j = 0; j < 4; ++j)
        tile[ty + j * 8][tx] = W[(size_t)(by + ty + j * 8) * N + bx + tx];
    __syncthreads();
#pragma unroll
    for (int j = 0; j < 4; ++j)
        Wt[(size_t)(bx + ty + j * 8) * K + by + tx] = (bf16)tile[tx][ty + j * 8];
}

// ---------------- bf16 MFMA GEMM: C = A(M x ldk) * Bt(N x ldk)^T, 128x128 tile ----------------
// K = slice length along k (blockIdx.z selects slice); ldk = full row stride.
// EPI: 0 = store bf16 raw; 2 = +bias,gelu store bf16; 4 = raw fp32 partial to (z ? C2 : C).
template <int EPI>
__global__ __launch_bounds__(256, 3) void gemm_bt(const bf16* __restrict__ A,
                                                  const bf16* __restrict__ Bt,
                                                  void* __restrict__ C,
                                                  void* __restrict__ C2,
                                                  const float* __restrict__ bias,
                                                  int M, int N, int K, int ldk) {
    __shared__ __align__(16) bf16 As[128 * 64];
    __shared__ __align__(16) bf16 Bs[128 * 64];
    const int tid  = threadIdx.x;
    const int lane = tid & 63;
    const int wave = tid >> 6;
    const int l16  = lane & 15;
    const int quad = lane >> 4;
    const int wm = wave >> 1, wn = wave & 1;
    const int m0 = blockIdx.y * 128, n0 = blockIdx.x * 128;
    const int z  = blockIdx.z;
    A  += (size_t)z * K;
    Bt += (size_t)z * K;

    f32x4 acc[4][4];
#pragma unroll
    for (int i = 0; i < 4; ++i)
#pragma unroll
        for (int j = 0; j < 4; ++j) acc[i][j] = (f32x4){0.f, 0.f, 0.f, 0.f};

    const int nsteps = K >> 6;
    for (int kt = 0; kt < nsteps; ++kt) {
        const int kbase = kt << 6;
#pragma unroll
        for (int c = 0; c < 4; ++c) {
            int chunk = wave * 4 + c;
            int gi = chunk * 64 + lane;
            int m  = gi >> 3;
            int cp = gi & 7;
            int g  = cp ^ (m & 7);
            stage16(A  + (size_t)(m0 + m) * ldk + kbase + g * 8, As + chunk * 512, lane);
            stage16(Bt + (size_t)(n0 + m) * ldk + kbase + g * 8, Bs + chunk * 512, lane);
        }
        __syncthreads();
#pragma unroll
        for (int ks = 0; ks < 2; ++ks) {
            bf16x8 af[4], bfr[4];
#pragma unroll
            for (int i = 0; i < 4; ++i) {
                int m = wm * 64 + i * 16 + l16;
                int g = ks * 4 + quad;
                af[i]  = *(const bf16x8*)(As + m * 64 + ((g ^ (m & 7)) * 8));
                int n = wn * 64 + i * 16 + l16;
                bfr[i] = *(const bf16x8*)(Bs + n * 64 + ((g ^ (n & 7)) * 8));
            }
#pragma unroll
            for (int i = 0; i < 4; ++i)
#pragma unroll
                for (int j = 0; j < 4; ++j)
                    acc[i][j] = __builtin_amdgcn_mfma_f32_16x16x32_bf16(af[i], bfr[j], acc[i][j], 0, 0, 0);
        }
        __syncthreads();
    }

    float* Cz = (EPI == 4) ? (z ? (float*)C2 : (float*)C) : nullptr;
#pragma unroll
    for (int i = 0; i < 4; ++i) {
        int row = m0 + wm * 64 + i * 16 + quad * 4;
#pragma unroll
        for (int j = 0; j < 4; ++j) {
            int col = n0 + wn * 64 + j * 16 + l16;
            float bv = (EPI == 2) ? bias[col] : 0.f;
#pragma unroll
            for (int r = 0; r < 4; ++r) {
                float v = acc[i][j][r];
                if (EPI == 2) v = gelu_exact(v + bv);
                size_t idx = (size_t)(row + r) * N + col;
                if (EPI == 4) Cz[idx] = v;
                else          ((bf16*)C)[idx] = (bf16)v;
            }
        }
    }
}

// ---------------- flash attention (r10: 512-thread blocks, staging amortized 2x) ----------------
// grid: (S/128, B*H), block 512 (8 waves; wave owns 16 query rows; 128 q-rows/block).
// Same K/V LDS tiles as r9 (Ks 128x64 swizzled, Vts 64x136 permuted) but staged once per
// 128 q-rows instead of once per 64: per-output staging cost (global fetch + LDS commit
// + prefetch regs) halves. Per-CU residency unchanged (2 blocks x 8 waves = 16 waves).
//   * K(kt+1)/V(kt+1)/mask(kt+1) prefetched into regs after the second barrier (T14).
//   * SCL folded into Q at load.
//   * lsum via ones-MFMA (row-sums land in C/D layout row=quad*4+r).
//   * s_setprio(1) around MFMA clusters (T5).
__global__ __launch_bounds__(512, 4) void flash_attn(const bf16* __restrict__ qkv,
                                                     const unsigned long long* __restrict__ maskb,
                                                     bf16* __restrict__ o) {
    __shared__ __align__(16) bf16 Ks[128 * 64];    // swizzled packed [t][g^(t&7)]
    __shared__ __align__(16) bf16 Vts[64 * 136];   // [d][tc], tc = t-permuted, pad 8
    const int tid  = threadIdx.x;
    const int lane = tid & 63;
    const int wave = tid >> 6;      // 0..7
    const int l16  = lane & 15;
    const int quad = lane >> 4;
    const int bh = blockIdx.y;
    const int b = bh >> 4, h = bh & 15;
    const int q0 = blockIdx.x * 128;
    const size_t rowb = (size_t)b * SS;
    const float SCL = 0.18033688011112042f;  // 0.125 * log2(e)

    // Q fragments, pre-scaled by SCL (so softmax is exp2(st) directly)
    const size_t qrow = (rowb + q0 + wave * 16 + l16) * 3072 + h * 64;
    bf16x8 qf[2];
    {
        bf16x8 q0r = *(const bf16x8*)(qkv + qrow + quad * 8);
        bf16x8 q1r = *(const bf16x8*)(qkv + qrow + 32 + quad * 8);
#pragma unroll
        for (int j = 0; j < 8; ++j) {
            qf[0][j] = (bf16)((float)q0r[j] * SCL);
            qf[1][j] = (bf16)((float)q1r[j] * SCL);
        }
    }

    f32x4 oacc[4];
#pragma unroll
    for (int d = 0; d < 4; ++d) oacc[d] = (f32x4){0.f, 0.f, 0.f, 0.f};
    f32x4 lacc = (f32x4){0.f, 0.f, 0.f, 0.f};
    const int mrow32 = (q0 + wave * 16 + l16) * 32;

    bf16x8 ones;
#pragma unroll
    for (int j = 0; j < 8; ++j) ones[j] = (bf16)1.0f;

    // V staging geometry: thread handles t-pair = 2*lane for d-granule d8 = wave*8;
    // permuted col tc groups the 8 k-slots of each (kc,quad) contiguously.
    const int vt_tc = (lane >> 4) * 32 + ((lane >> 1) & 3) * 8 + ((lane >> 3) & 1) * 4 + 2 * (lane & 1);
    const int vd8 = wave * 8;

    // K staging geometry (constant across kt): 2 chunks per wave
    int kst[2], ksg[2];
#pragma unroll
    for (int c = 0; c < 2; ++c) {
        int gi = (wave * 2 + c) * 64 + lane;
        kst[c] = gi >> 3;
        ksg[c] = (gi & 7) ^ (kst[c] & 7);
    }

    // -------- prologue: prefetch tile 0 into registers --------
    bf16x8 kreg[2], vreg[2];
    ulonglong2 mwreg;
#pragma unroll
    for (int c = 0; c < 2; ++c)
        kreg[c] = *(const bf16x8*)(qkv + (rowb + kst[c]) * 3072 + 1024 + h * 64 + ksg[c] * 8);
    {
        const bf16* vg = qkv + (rowb + 2 * lane) * 3072 + 2048 + h * 64 + vd8;
        vreg[0] = *(const bf16x8*)(vg);
        vreg[1] = *(const bf16x8*)(vg + 3072);
    }
    mwreg = *(const ulonglong2*)(maskb + mrow32);

    for (int kt = 0; kt < SS / 128; ++kt) {
        __syncthreads();  // previous tile's compute done before overwrite
        // commit staged K (swizzled layout identical to r9)
#pragma unroll
        for (int c = 0; c < 2; ++c)
            *(bf16x8*)(Ks + (wave * 2 + c) * 512 + lane * 8) = kreg[c];
        // commit staged V, transposed+permuted (8 bf16x2 writes per thread)
#pragma unroll
        for (int j = 0; j < 8; ++j) {
            bf16x2 pr; pr[0] = vreg[0][j]; pr[1] = vreg[1][j];
            *(bf16x2*)(Vts + (vd8 + j) * 136 + vt_tc) = pr;
        }
        ulonglong2 mw = mwreg;
        __syncthreads();

        // prefetch next tile into regs: latency hides under this tile's compute.
        // (must be AFTER the barrier: __syncthreads drains vmcnt(0).)
        if (kt + 1 < SS / 128) {
            const int t0n = (kt + 1) * 128;
#pragma unroll
            for (int c = 0; c < 2; ++c)
                kreg[c] = *(const bf16x8*)(qkv + (rowb + t0n + kst[c]) * 3072 + 1024 + h * 64 + ksg[c] * 8);
            {
                const bf16* vg = qkv + (rowb + t0n + 2 * lane) * 3072 + 2048 + h * 64 + vd8;
                vreg[0] = *(const bf16x8*)(vg);
                vreg[1] = *(const bf16x8*)(vg + 3072);
            }
            mwreg = *(const ulonglong2*)(maskb + mrow32 + (kt + 1) * 2);
        }

        // S^T tiles: D[t][s], t = tg*16 + quad*4 + reg, s = l16
        f32x4 st[8];
        __builtin_amdgcn_s_setprio(1);
#pragma unroll
        for (int tg = 0; tg < 8; ++tg) {
            int tl = tg * 16 + l16;
            bf16x8 a0 = *(const bf16x8*)(Ks + tl * 64 + ((quad       ^ (tl & 7)) * 8));
            bf16x8 a1 = *(const bf16x8*)(Ks + tl * 64 + (((4 + quad) ^ (tl & 7)) * 8));
            f32x4 s = (f32x4){0.f, 0.f, 0.f, 0.f};
            s = __builtin_amdgcn_mfma_f32_16x16x32_bf16(a0, qf[0], s, 0, 0, 0);
            s = __builtin_amdgcn_mfma_f32_16x16x32_bf16(a1, qf[1], s, 0, 0, 0);
            st[tg] = s;
        }
        __builtin_amdgcn_s_setprio(0);

        // exp2 + mask-zero + pack P fragments (Q pre-scaled: no mul here)
        unsigned long long s0 = mw.x >> (quad * 4);
        unsigned long long s1 = mw.y >> (quad * 4);
        bf16x8 pva[4];
#pragma unroll
        for (int tg = 0; tg < 8; ++tg) {
            unsigned int bits = (unsigned int)(((tg < 4) ? s0 : s1) >> ((tg & 3) * 16));
#pragma unroll
            for (int r = 0; r < 4; ++r) {
                float p = __builtin_amdgcn_exp2f(st[tg][r]);
                p = ((bits >> r) & 1u) ? 0.f : p;
                pva[tg >> 1][(tg & 1) * 4 + r] = (bf16)p;
            }
        }

        // O += P*V ; lsum += P*ones (row-sums on the MFMA pipe, layout row=quad*4+r)
        __builtin_amdgcn_s_setprio(1);
#pragma unroll
        for (int kc = 0; kc < 4; ++kc) {
#pragma unroll
            for (int dg = 0; dg < 4; ++dg) {
                bf16x8 bfrag = *(const bf16x8*)(Vts + (dg * 16 + l16) * 136 + kc * 32 + quad * 8);
                oacc[dg] = __builtin_amdgcn_mfma_f32_16x16x32_bf16(pva[kc], bfrag, oacc[dg], 0, 0, 0);
            }
            lacc = __builtin_amdgcn_mfma_f32_16x16x32_bf16(pva[kc], ones, lacc, 0, 0, 0);
        }
        __builtin_amdgcn_s_setprio(0);
    }

    // epilogue: lacc[r] already holds the P row-sum for q-row quad*4+r
#pragma unroll
    for (int r = 0; r < 4; ++r) {
        float inv_l = 1.f / lacc[r];
        bf16* orow = o + (rowb + q0 + wave * 16 + quad * 4 + r) * DD + h * 64;
#pragma unroll
        for (int dg = 0; dg < 4; ++dg)
            orow[dg * 16 + l16] = (bf16)(oacc[dg][r] * inv_l);
    }
}

// ---------------- fused split-K reduce + bias (+gelu) + residual LayerNorm ----------------
// out = resid + LN(act(p0 + p1 + bias)) * g + b ;  act = gelu if GELU else identity
template <bool GELU, bool WB16>
__global__ __launch_bounds__(256) void ln_fused(const float* __restrict__ resid,
                                                const float* __restrict__ p0,
                                                const float* __restrict__ p1,
                                                const float* __restrict__ bias,
                                                const float* __restrict__ g,
                                                const float* __restrict__ bb,
                                                float* __restrict__ outf,
                                                bf16* __restrict__ outb) {
    const int row = blockIdx.x;
    const int tid = threadIdx.x;
    const size_t base = (size_t)row * DD + tid * 4;
    float4 a0 = *(const float4*)(p0 + base);
    float4 a1 = *(const float4*)(p1 + base);
    float4 bz = *(const float4*)(bias + tid * 4);
    float ax = a0.x + a1.x + bz.x;
    float ay = a0.y + a1.y + bz.y;
    float az = a0.z + a1.z + bz.z;
    float aw = a0.w + a1.w + bz.w;
    if (GELU) { ax = gelu_exact(ax); ay = gelu_exact(ay); az = gelu_exact(az); aw = gelu_exact(aw); }
    float s1 = ax + ay + az + aw;
    float s2 = ax * ax + ay * ay + az * az + aw * aw;
#pragma unroll
    for (int off = 32; off; off >>= 1) {
        s1 += __shfl_xor(s1, off, 64);
        s2 += __shfl_xor(s2, off, 64);
    }
    __shared__ float red[8];
    if ((tid & 63) == 0) { red[(tid >> 6) * 2] = s1; red[(tid >> 6) * 2 + 1] = s2; }
    __syncthreads();
    s1 = red[0] + red[2] + red[4] + red[6];
    s2 = red[1] + red[3] + red[5] + red[7];
    float mean = s1 * (1.f / DD);
    float var  = s2 * (1.f / DD) - mean * mean;
    float rs = rsqrtf(var + 1e-5f);
    float4 gv = *(const float4*)(g + tid * 4);
    float4 bv = *(const float4*)(bb + tid * 4);
    float4 rv = *(const float4*)(resid + base);
    float y0 = rv.x + (ax - mean) * rs * gv.x + bv.x;
    float y1 = rv.y + (ay - mean) * rs * gv.y + bv.y;
    float y2 = rv.z + (az - mean) * rs * gv.z + bv.z;
    float y3 = rv.w + (aw - mean) * rs * gv.w + bv.w;
    float4 yo = make_float4(y0, y1, y2, y3);
    *(float4*)(outf + base) = yo;
    if (WB16) {
        bf16x4 ob;
        ob[0] = (bf16)y0; ob[1] = (bf16)y1; ob[2] = (bf16)y2; ob[3] = (bf16)y3;
        *(bf16x4*)(outb + base) = ob;
    }
}

// ---------------- launcher ----------------
extern "C" void kernel_launch(void* const* d_in, const int* in_sizes, int n_in,
                              void* d_out, int out_size, void* d_ws, size_t ws_size,
                              hipStream_t stream) {
    const float* x    = (const float*)d_in[0];
    const int*   mask = (const int*)d_in[1];
    const float* Wq   = (const float*)d_in[2];
    const float* Wk   = (const float*)d_in[3];
    const float* Wv   = (const float*)d_in[4];
    const float* Wo   = (const float*)d_in[5];
    const float* bo   = (const float*)d_in[6];
    const float* ln1g = (const float*)d_in[7];
    const float* ln1b = (const float*)d_in[8];
    const float* W1   = (const float*)d_in[9];
    const float* b1   = (const float*)d_in[10];
    const float* W2   = (const float*)d_in[11];
    const float* b2   = (const float*)d_in[12];
    const float* ln2g = (const float*)d_in[13];
    const float* ln2b = (const float*)d_in[14];

    char* w = (char*)d_ws;
    bf16* Wqkv_t = (bf16*)w; w += (size_t)3072 * 1024 * 2;   // 6 MB
    bf16* Wo_t   = (bf16*)w; w += (size_t)1024 * 1024 * 2;   // 2 MB
    bf16* W1_t   = (bf16*)w; w += (size_t)4096 * 1024 * 2;   // 8 MB
    bf16* W2_t   = (bf16*)w; w += (size_t)1024 * 4096 * 2;   // 8 MB
    bf16* x_b    = (bf16*)w; w += (size_t)MROWS * DD * 2;    // 8 MB (then o_b, x1_b)
    bf16* qkv    = (bf16*)w; w += (size_t)MROWS * 3072 * 2;  // 24 MB (then FFN2 p1)
    float* R     = (float*)w; w += (size_t)MROWS * DD * 8;   // 32 MB (O-proj p0/p1, then h_b)
    float* x1_f  = (float*)w; w += (size_t)MROWS * DD * 4;   // 16 MB
    unsigned long long* maskb = (unsigned long long*)w; w += (size_t)SS * 32 * 8;  // 0.5 MB  (total 104.5)
    bf16* o_b  = x_b;                 // alive: attention -> O-proj
    bf16* x1_b = x_b;                 // alive: LN1 -> FFN1
    float* op0 = R;                   // O-proj partial z=0
    float* op1 = R + (size_t)MROWS * DD;  // O-proj partial z=1
    bf16*  h_b = (bf16*)R;            // FFN1 out (32 MB; partials dead by then)
    float* fp0 = (float*)d_out;       // FFN2 partial z=0 (reduced in-place by LN2)
    float* fp1 = (float*)qkv;         // FFN2 partial z=1 (qkv dead after flash)

    // fused prep (one launch)
    prep_kernel<<<32768, 256, 0, stream>>>(x, x_b, mask, maskb,
                                           Wq, Wk, Wv, Wo, W1, W2,
                                           Wqkv_t, Wo_t, W1_t, W2_t);

    // QKV projection: [4096,1024] x [1024,3072] -> qkv bf16
    gemm_bt<0><<<dim3(24, 32, 1), 256, 0, stream>>>(x_b, Wqkv_t, qkv, nullptr, nullptr, MROWS, 3072, 1024, 1024);
    // attention (512-thread blocks, 128 q-rows each)
    flash_attn<<<dim3(SS / 128, BB * HH), 512, 0, stream>>>(qkv, maskb, o_b);
    // O-proj, split-K=2 -> fp32 partials (bias deferred to LN1)
    gemm_bt<4><<<dim3(8, 32, 2), 256, 0, stream>>>(o_b, Wo_t, op0, op1, nullptr, MROWS, 1024, 512, 1024);
    // x1 = x + LN(op0+op1+bo)
    ln_fused<false, true><<<MROWS, 256, 0, stream>>>(x, op0, op1, bo, ln1g, ln1b, x1_f, x1_b);
    // FFN1: gelu(x1@W1 + b1) -> bf16
    gemm_bt<2><<<dim3(32, 32, 1), 256, 0, stream>>>(x1_b, W1_t, h_b, nullptr, b1, MROWS, 4096, 1024, 1024);
    // FFN2, split-K=2 -> fp32 partials (bias+gelu deferred to LN2)
    gemm_bt<4><<<dim3(8, 32, 2), 256, 0, stream>>>(h_b, W2_t, fp0, fp1, nullptr, MROWS, 1024, 2048, 4096);
    // out = x1 + LN(gelu(fp0+fp1+b2))  (fp32, in-place on d_out)
    ln_fused<true, false><<<MROWS, 256, 0, stream>>>(x1_f, fp0, fp1, b2, ln2g, ln2b, (float*)d_out, nullptr);
}